// Round 1
// baseline (73.847 us; speedup 1.0000x reference)
//
#include <hip/hip_runtime.h>

// NALU B=1024, I=512, O=512 — SINGLE fused dispatch, fp16 MFMA 16x16x32.
//   w1 = tanh(w_hat)*sigmoid(m_hat); a = x@w1; s = log(max(|x|,eps))@w1
//   m1 = exp(min(s,20)); out = g1*a + (1-g1)*m1*clip(ms,-1,1)
// s ~ N(-143,11^2) => m1 underflows to 0; guarded exactly: any s > -80
// takes a cold path computing the true sign-product from wh/mh.
//
// Fusion rationale (R0 of this session): previous 2-dispatch version staged
// frags through d_ws; harness re-poisons the 268MB workspace every timed
// iteration (43us fillBuffer in rocprof) and we paid 2 launches + a frag
// round-trip. This version touches d_ws NEVER:
//   phase 1: each block computes its w1 tile (512k x 32o) cooperatively,
//            directly in MFMA frag order, into 32KB LDS (lane-contiguous
//            16B ds_write_b128 -> conflict-free).
//   phase 2: dual GEMM; A-frags (x, log|x|) built on the fly from float4
//            reads of x (frag k-runs contiguous in memory), B-frags from
//            LDS (lane-contiguous ds_read_b128 -> conflict-free).
// Block tile 64b x 32o, 8 waves (4 tm x 2 tn), grid (16,16)=256 blocks
// = 1 block/CU = 2 waves/SIMD. w1 recompute redundancy 16x (b-blocks):
// ~4.2M tanh*sigmoid pairs device-wide ~ 0.4us of trans-unit time.
// Frag layouts (learn_hip-verified): A[m=lane&15][k=(lane>>4)*8+j],
// B[k=(lane>>4)*8+j][n=lane&15], D[m=(lane>>4)*4+reg][n=lane&15].

#define O_N 512
#define I_N 512
#define B_N 1024

typedef _Float16 f16;
typedef _Float16 f16x8 __attribute__((ext_vector_type(8)));
typedef float f32x4 __attribute__((ext_vector_type(4)));

__device__ __forceinline__ float fast_sigmoid(float v) {
    return 1.0f / (1.0f + __expf(-v));
}
__device__ __forceinline__ float fast_tanh(float v) {
    return 1.0f - 2.0f / (1.0f + __expf(2.0f * v));   // exact at both tails
}

__global__ __launch_bounds__(512, 2)
void nalu_fused_kernel(const float* __restrict__ x,
                       const float* __restrict__ wh,
                       const float* __restrict__ mh,
                       const float* __restrict__ g,
                       float* __restrict__ out) {
    // B frags for this block: f = tn*16 + kb, 32 frags x 64 lanes x 16B = 32KB
    __shared__ f16x8 bsh[32 * 64];

    const int lane  = threadIdx.x & 63;
    const int w     = threadIdx.x >> 6;     // 0..7
    const int o_blk = blockIdx.x * 32;
    const int b_blk = blockIdx.y * 64;

    // ---- phase 1: cooperative B-frag prep (w1 = tanh(wh)*sigmoid(mh))
    {
        const int rk = (lane >> 4) * 8;     // frag-k base within the 32-k tile
        const int cn = lane & 15;
#pragma unroll
        for (int q = 0; q < 4; ++q) {
            const int f     = w * 4 + q;    // 0..31, wave w owns 4 frags
            const int kb_f  = f & 15;
            const int n     = o_blk + (f >> 4) * 16 + cn;
            const int kbase = kb_f * 32 + rk;
            const float* wp = wh + kbase * O_N + n;
            const float* mp = mh + kbase * O_N + n;
            f16x8 bf;
#pragma unroll
            for (int j = 0; j < 8; ++j) {
                const float wv = wp[j * O_N];
                const float mv = mp[j * O_N];
                bf[j] = (f16)(fast_tanh(wv) * fast_sigmoid(mv));
            }
            bsh[f * 64 + lane] = bf;        // lane-contiguous ds_write_b128
        }
    }
    __syncthreads();

    // ---- phase 2: dual GEMM (a-path and s-path share the B frag)
    const int tm = w & 3;                   // 4 b-subtiles of 16
    const int tn = w >> 2;                  // 2 o-subtiles of 16
    const int b0 = b_blk + tm * 16;
    const int o0 = o_blk + tn * 16;

    const int m    = b0 + (lane & 15);
    const int k0l  = (lane >> 4) * 8;
    const float* xrow = x + m * I_N + k0l;
    const f16x8* bsw  = bsh + tn * 16 * 64 + lane;

    f32x4 ca = {0.f, 0.f, 0.f, 0.f}, cs = ca;
#pragma unroll
    for (int kb = 0; kb < 16; ++kb) {
        const f16x8 bf = bsw[kb * 64];                       // ds_read_b128
        const float4 q0 = *(const float4*)(xrow + kb * 32);  // k-contiguous
        const float4 q1 = *(const float4*)(xrow + kb * 32 + 4);
        const float vx[8] = {q0.x, q0.y, q0.z, q0.w, q1.x, q1.y, q1.z, q1.w};
        f16x8 ax, al;
#pragma unroll
        for (int j = 0; j < 8; ++j) {
            ax[j] = (f16)vx[j];
            al[j] = (f16)__logf(fmaxf(fabsf(vx[j]), 1e-7f));
        }
        ca = __builtin_amdgcn_mfma_f32_16x16x32_f16(ax, bf, ca, 0, 0, 0);
        cs = __builtin_amdgcn_mfma_f32_16x16x32_f16(al, bf, cs, 0, 0, 0);
    }

    // ---- epilogue: D[m=(lane>>4)*4+r][n=lane&15]
    const int col = lane & 15;
    const int rq  = (lane >> 4) * 4;
    const int o   = o0 + col;
    const float g1  = fast_sigmoid(g[o]);
    const float omg = 1.0f - g1;
#pragma unroll
    for (int r = 0; r < 4; ++r) {
        const int b = b0 + rq + r;
        const float sv = cs[r];
        const float m1 = __expf(fminf(sv, 20.0f));
        float msv = 1.0f;
        if (sv > -80.0f) {                  // cold path (expected never): exact ms
            float p = 1.0f;
            for (int i = 0; i < I_N; ++i) {
                // ws_oi[o][i] = |w1.flat[o*I+i]| = |w1[row=o][col=i]|
                const float wv = fabsf(fast_tanh(wh[o * I_N + i]) *
                                       fast_sigmoid(mh[o * I_N + i]));
                const float xv = x[b * I_N + i];
                const float sg = (xv > 0.f) ? 1.f : ((xv < 0.f) ? -1.f : 0.f);
                p *= sg * wv + (1.0f - wv);
            }
            msv = fminf(fmaxf(p, -1.0f), 1.0f);
        }
        out[b * O_N + o] = g1 * ca[r] + omg * m1 * msv;
    }
}

extern "C" void kernel_launch(void* const* d_in, const int* in_sizes, int n_in,
                              void* d_out, int out_size, void* d_ws, size_t ws_size,
                              hipStream_t stream) {
    const float* x  = (const float*)d_in[0];   // [B, I]
    const float* wh = (const float*)d_in[1];   // [I, O]
    const float* mh = (const float*)d_in[2];   // [I, O]
    const float* g  = (const float*)d_in[3];   // [O]
    float* out = (float*)d_out;                // [B, O] fp32
    (void)d_ws; (void)ws_size;                 // workspace intentionally unused

    nalu_fused_kernel<<<dim3(16, 16), 512, 0, stream>>>(x, wh, mh, g, out);
}